// Round 1
// baseline (43.967 us; speedup 1.0000x reference)
//
#include <hip/hip_runtime.h>

// MorphTEmbedding: per-token direct computation.
// out[b,t,:] = LayerNorm( sum_r outer3(W[r, co[x,0]], W[r, co[x,1]], W[r, co[x,2]]) )
// EMB_DIM = 8^3 = 512 exactly, so the [:, :EMB_DIM] slice in the reference is a no-op.

#define RANK      8
#define NUM_MORPH 10000
#define CORE_DIM  8
#define ORDER     3
#define EMB       512
#define LN_EPS    1e-5f

__device__ __forceinline__ float wave_reduce_sum(float v) {
#pragma unroll
    for (int off = 32; off > 0; off >>= 1) v += __shfl_xor(v, off);
    return v;
}

__global__ __launch_bounds__(512) void morph_emb_kernel(
    const int* __restrict__ x,       // [n_tok] surface ids (int32 per harness convention)
    const int* __restrict__ co,      // [NUM_SURF, 3] morpheme ids
    const float* __restrict__ W,     // [RANK, NUM_MORPH, CORE_DIM]
    const float* __restrict__ lns,   // [EMB]
    const float* __restrict__ lnb,   // [EMB]
    float* __restrict__ out,         // [n_tok, EMB]
    int n_tok) {
    const int token = blockIdx.x;
    if (token >= n_tok) return;
    const int tid = threadIdx.x;

    __shared__ float c[RANK][ORDER][CORE_DIM];   // 192 floats
    __shared__ float red1[8], red2[8];

    const int s = x[token];

    // Stage the 8x3x8 core block into LDS (first 192 threads).
    if (tid < RANK * ORDER * CORE_DIM) {
        const int r   = tid / (ORDER * CORE_DIM);
        const int rem = tid - r * (ORDER * CORE_DIM);
        const int o   = rem >> 3;
        const int d   = rem & 7;
        const int m   = co[s * ORDER + o];
        c[r][o][d] = W[(r * NUM_MORPH + m) * CORE_DIM + d];
    }
    __syncthreads();

    // element index e = tid = a*64 + b*8 + cc  (matches reference reshape order)
    const int a  = tid >> 6;
    const int b  = (tid >> 3) & 7;
    const int cc = tid & 7;

    float v = 0.f;
#pragma unroll
    for (int r = 0; r < RANK; ++r)
        v += (c[r][0][a] * c[r][1][b]) * c[r][2][cc];

    // ---- LayerNorm over the 512 elements of this block ----
    const int wave = tid >> 6;
    const int lane = tid & 63;

    float s1 = wave_reduce_sum(v);
    if (lane == 0) red1[wave] = s1;
    __syncthreads();
    float tot = 0.f;
#pragma unroll
    for (int w = 0; w < 8; ++w) tot += red1[w];
    const float mu = tot * (1.0f / EMB);

    const float d0 = v - mu;
    float s2 = wave_reduce_sum(d0 * d0);
    if (lane == 0) red2[wave] = s2;
    __syncthreads();
    float tot2 = 0.f;
#pragma unroll
    for (int w = 0; w < 8; ++w) tot2 += red2[w];
    const float var = tot2 * (1.0f / EMB);
    const float rs  = rsqrtf(var + LN_EPS);

    out[(size_t)token * EMB + tid] = d0 * rs * lns[tid] + lnb[tid];
}

extern "C" void kernel_launch(void* const* d_in, const int* in_sizes, int n_in,
                              void* d_out, int out_size, void* d_ws, size_t ws_size,
                              hipStream_t stream) {
    const int*   x   = (const int*)d_in[0];    // [BATCH*SEQ]
    const int*   co  = (const int*)d_in[1];    // [NUM_SURF*3]
    const float* W   = (const float*)d_in[2];  // [8*10000*8]
    const float* lns = (const float*)d_in[3];  // [512]
    const float* lnb = (const float*)d_in[4];  // [512]
    float*       out = (float*)d_out;

    const int n_tok = in_sizes[0];             // 8*2048 = 16384
    morph_emb_kernel<<<n_tok, EMB, 0, stream>>>(x, co, W, lns, lnb, out, n_tok);
}

// Round 2
// 16.887 us; speedup vs baseline: 2.6036x; 2.6036x over previous
//
#include <hip/hip_runtime.h>

// MorphTEmbedding: one wave (64 lanes) per token; each lane computes 8
// consecutive embedding elements. e = lane*8+j  =>  a=lane>>3, b=lane&7, cc=j
// out[tok, e] = LN( sum_r W[r,m0,a] * W[r,m1,b] * W[r,m2,j] )

#define RANK      8
#define NUM_MORPH 10000
#define EMB       512
#define LN_EPS    1e-5f
#define WPB       4        // waves per block -> 256 threads

__global__ __launch_bounds__(256) void morph_emb_kernel(
    const int* __restrict__ x,       // [n_tok]
    const int* __restrict__ co,      // [NUM_SURF, 3]
    const float* __restrict__ W,     // [RANK, NUM_MORPH, 8]
    const float* __restrict__ lns,   // [512]
    const float* __restrict__ lnb,   // [512]
    float* __restrict__ out,         // [n_tok, 512]
    int n_tok) {
    const int lane  = threadIdx.x & 63;
    const int wave  = threadIdx.x >> 6;
    const int token = blockIdx.x * WPB + wave;

    __shared__ float cbuf[WPB][3][RANK][8];   // 3 KB

    if (token < n_tok && lane < 48) {
        const int s    = x[token];
        const int ro   = lane >> 1;          // 0..23
        const int o    = ro >> 3;            // 0..2
        const int r    = ro & 7;             // 0..7
        const int half = (lane & 1) << 2;    // 0 or 4
        const int m    = co[s * 3 + o];
        const float4 v = *reinterpret_cast<const float4*>(
            &W[(size_t)(r * NUM_MORPH + m) * 8 + half]);
        *reinterpret_cast<float4*>(&cbuf[wave][o][r][half]) = v;
    }
    __syncthreads();
    if (token >= n_tok) return;

    const int ia = lane >> 3;
    const int ib = lane & 7;

    float v0[4] = {0.f, 0.f, 0.f, 0.f};
    float v1[4] = {0.f, 0.f, 0.f, 0.f};
#pragma unroll
    for (int r = 0; r < RANK; ++r) {
        const float  p  = cbuf[wave][0][r][ia] * cbuf[wave][1][r][ib];
        const float4 q0 = *reinterpret_cast<const float4*>(&cbuf[wave][2][r][0]);
        const float4 q1 = *reinterpret_cast<const float4*>(&cbuf[wave][2][r][4]);
        v0[0] += p * q0.x; v0[1] += p * q0.y; v0[2] += p * q0.z; v0[3] += p * q0.w;
        v1[0] += p * q1.x; v1[1] += p * q1.y; v1[2] += p * q1.z; v1[3] += p * q1.w;
    }

    // ---- LayerNorm (fully intra-wave: 64 lanes x 8 elems = 512) ----
    float s1 = ((v0[0] + v0[1]) + (v0[2] + v0[3])) +
               ((v1[0] + v1[1]) + (v1[2] + v1[3]));
#pragma unroll
    for (int off = 32; off > 0; off >>= 1) s1 += __shfl_xor(s1, off);
    const float mu = s1 * (1.0f / EMB);

    float d0[4], d1[4];
    float s2 = 0.f;
#pragma unroll
    for (int j = 0; j < 4; ++j) { d0[j] = v0[j] - mu; s2 += d0[j] * d0[j]; }
#pragma unroll
    for (int j = 0; j < 4; ++j) { d1[j] = v1[j] - mu; s2 += d1[j] * d1[j]; }
#pragma unroll
    for (int off = 32; off > 0; off >>= 1) s2 += __shfl_xor(s2, off);
    const float rs = rsqrtf(s2 * (1.0f / EMB) + LN_EPS);

    const int e = lane << 3;
    const float4 g0 = *reinterpret_cast<const float4*>(&lns[e]);
    const float4 g1 = *reinterpret_cast<const float4*>(&lns[e + 4]);
    const float4 b0 = *reinterpret_cast<const float4*>(&lnb[e]);
    const float4 b1 = *reinterpret_cast<const float4*>(&lnb[e + 4]);

    float4 o0, o1;
    o0.x = d0[0] * rs * g0.x + b0.x;
    o0.y = d0[1] * rs * g0.y + b0.y;
    o0.z = d0[2] * rs * g0.z + b0.z;
    o0.w = d0[3] * rs * g0.w + b0.w;
    o1.x = d1[0] * rs * g1.x + b1.x;
    o1.y = d1[1] * rs * g1.y + b1.y;
    o1.z = d1[2] * rs * g1.z + b1.z;
    o1.w = d1[3] * rs * g1.w + b1.w;

    float* op = out + (size_t)token * EMB + e;
    *reinterpret_cast<float4*>(op)     = o0;
    *reinterpret_cast<float4*>(op + 4) = o1;
}

extern "C" void kernel_launch(void* const* d_in, const int* in_sizes, int n_in,
                              void* d_out, int out_size, void* d_ws, size_t ws_size,
                              hipStream_t stream) {
    const int*   x   = (const int*)d_in[0];
    const int*   co  = (const int*)d_in[1];
    const float* W   = (const float*)d_in[2];
    const float* lns = (const float*)d_in[3];
    const float* lnb = (const float*)d_in[4];
    float*       out = (float*)d_out;

    const int n_tok  = in_sizes[0];                 // 16384
    const int blocks = (n_tok + WPB - 1) / WPB;     // 4096
    morph_emb_kernel<<<blocks, WPB * 64, 0, stream>>>(x, co, W, lns, lnb, out, n_tok);
}